// Round 1
// baseline (13097.366 us; speedup 1.0000x reference)
//
#include <hip/hip_runtime.h>
#include <hip/hip_fp16.h>

#define SEQ   2048
#define IND   256
#define NN    256
// W_g: [512,512] rows 0..255 = x-part, 256..511 = h-part. W_c: [512,256].

// ---------------- K0: pack recurrent (h-part) weights into k-grouped float4 ----
// WGP[k4*512 + j] = {W_g[256+4k4+e][j]}e=0..3   (k4<64, j<512)
// WCP[k4*256 + n] = {W_c[256+4k4+e][n]}        (k4<64, n<256)
__global__ void pack_weights(const float* __restrict__ Wg,
                             const float* __restrict__ Wc,
                             float4* __restrict__ WGP,
                             float4* __restrict__ WCP) {
  int idx = blockIdx.x * 256 + threadIdx.x;
  if (idx < 64 * 512) {
    int k4 = idx >> 9, j = idx & 511;
    int r = 256 + k4 * 4;
    WGP[idx] = make_float4(Wg[(r+0)*512+j], Wg[(r+1)*512+j],
                           Wg[(r+2)*512+j], Wg[(r+3)*512+j]);
  } else {
    int i2 = idx - 64 * 512;          // < 64*256
    int k4 = i2 >> 8, n = i2 & 255;
    int r = 256 + k4 * 4;
    WCP[i2] = make_float4(Wc[(r+0)*256+n], Wc[(r+1)*256+n],
                          Wc[(r+2)*256+n], Wc[(r+3)*256+n]);
  }
}

// ---------------- K1: x-projection GEMM  C[i][j] = sum_k x[i][k]*Wx[k][j] ------
// j<512 -> W_g x-part, store f16 into XG (= d_out reused);  j>=512 -> W_c, XC in ws.
// No bias here (added f32 in the scan).
__global__ __launch_bounds__(256) void xproj_gemm(
    const float* __restrict__ x, const float* __restrict__ Wg,
    const float* __restrict__ Wc, __half* XG, __half* XC) {
  __shared__ float As[16][68];   // [k][i], pad to 68 (16B-aligned rows)
  __shared__ float Bs[16][64];   // [k][j]
  const int i0 = blockIdx.x * 64;
  const int j0 = blockIdx.y * 64;
  const int tid = threadIdx.x;
  const int tr = tid >> 4, tc = tid & 15;
  const int arow = tid >> 2, ac4 = (tid & 3) * 4;
  const int bk = tid >> 4, bj4 = (tid & 15) * 4;
  const bool isG = (j0 < 512);
  const float* B = isG ? Wg : Wc;
  const int ldb = isG ? 512 : 256;
  const int jb  = (isG ? j0 : (j0 - 512)) + bj4;
  float acc[4][4] = {};
  for (int k0 = 0; k0 < IND; k0 += 16) {
    float4 av = *(const float4*)&x[(size_t)(i0 + arow) * IND + k0 + ac4];
    As[ac4+0][arow] = av.x; As[ac4+1][arow] = av.y;
    As[ac4+2][arow] = av.z; As[ac4+3][arow] = av.w;
    *(float4*)&Bs[bk][bj4] = *(const float4*)&B[(size_t)(k0 + bk) * ldb + jb];
    __syncthreads();
#pragma unroll
    for (int k = 0; k < 16; ++k) {
      float4 a4 = *(const float4*)&As[k][tr * 4];
      float4 b4 = *(const float4*)&Bs[k][tc * 4];
      float a[4] = {a4.x, a4.y, a4.z, a4.w};
      float b[4] = {b4.x, b4.y, b4.z, b4.w};
#pragma unroll
      for (int r = 0; r < 4; ++r)
#pragma unroll
        for (int c = 0; c < 4; ++c) acc[r][c] = fmaf(a[r], b[c], acc[r][c]);
    }
    __syncthreads();
  }
  for (int r = 0; r < 4; ++r) {
    const size_t i = i0 + tr * 4 + r;
    const int j = j0 + tc * 4;
    __half2 p0 = __floats2half2_rn(acc[r][0], acc[r][1]);
    __half2 p1 = __floats2half2_rn(acc[r][2], acc[r][3]);
    union { __half2 h2[2]; uint2 u; } pk; pk.h2[0] = p0; pk.h2[1] = p1;
    if (isG) *(uint2*)&XG[i * 512 + j]            = pk.u;
    else     *(uint2*)&XC[i * 256 + (j - 512)]    = pk.u;
  }
}

// ---------------- K2: sequential GRU scan, one block per batch ------------------
// 512 threads: phase A thread j = gate col j (r: j<256, u: j>=256).
// phase B: cand col n = j&255, k-half = j>>8; thread 256+n holds u_n and finalizes.
__global__ __launch_bounds__(512) void gru_scan(
    const float4* __restrict__ WGP, const float4* __restrict__ WCP,
    const float* __restrict__ bg, const float* __restrict__ bc,
    const float* __restrict__ h0,
    const __half* XG, const __half* XC, float* out) {
  __shared__ float h[NN];
  __shared__ float rh[NN];
  __shared__ float cpart[NN];
  const int b = blockIdx.x;
  const int j = threadIdx.x;
  const int n = j & 255;
  const int kh = j >> 8;
  if (j < NN) h[j] = h0[b * NN + j];
  const float bgj = bg[j];
  const float bcn = bc[n];
  __syncthreads();
  const float4* hp = (const float4*)h;
  const float4* rp = (const float4*)rh;
  const size_t base = (size_t)b * SEQ;
  for (int t = 0; t < SEQ; ++t) {
    const size_t row = base + t;
    // ---- phase A: gates = sigmoid(xg + b_g + h @ Wgh[:,j])
    float g = bgj + __half2float(XG[row * 512 + j]);
#pragma unroll 8
    for (int k4 = 0; k4 < 64; ++k4) {
      float4 w  = WGP[(k4 << 9) + j];
      float4 hv = hp[k4];
      g = fmaf(hv.x, w.x, g); g = fmaf(hv.y, w.y, g);
      g = fmaf(hv.z, w.z, g); g = fmaf(hv.w, w.w, g);
    }
    g = 1.f / (1.f + __expf(-g));
    const float u = g;                 // valid for kh==1 threads (col n)
    if (j < NN) rh[j] = g * h[j];      // r * h
    __syncthreads();
    // ---- phase B: c = tanh(xc + b_c + (r*h) @ Wch[:,n]), split k across 2 threads
    float ca = (kh == 1) ? (bcn + __half2float(XC[row * 256 + n])) : 0.f;
#pragma unroll 8
    for (int kk = 0; kk < 32; ++kk) {
      const int k4 = kh * 32 + kk;
      float4 w  = WCP[(k4 << 8) + n];
      float4 rv = rp[k4];
      ca = fmaf(rv.x, w.x, ca); ca = fmaf(rv.y, w.y, ca);
      ca = fmaf(rv.z, w.z, ca); ca = fmaf(rv.w, w.w, ca);
    }
    if (kh == 0) cpart[n] = ca;
    __syncthreads();
    if (kh == 1) {
      const float c  = tanhf(ca + cpart[n]);
      const float hn = u * h[n] + (1.f - u) * c;
      out[row * 256 + n] = hn;   // overwrites this row's XG region (already consumed)
      h[n] = hn;
    }
    __syncthreads();
  }
}

extern "C" void kernel_launch(void* const* d_in, const int* in_sizes, int n_in,
                              void* d_out, int out_size, void* d_ws, size_t ws_size,
                              hipStream_t stream) {
  const float* x  = (const float*)d_in[0];
  const float* h0 = (const float*)d_in[1];
  const float* Wg = (const float*)d_in[2];
  const float* bg = (const float*)d_in[3];
  const float* Wc = (const float*)d_in[4];
  const float* bc = (const float*)d_in[5];

  char* ws = (char*)d_ws;
  __half* XC  = (__half*)ws;                        // 65536*256*2 = 33,554,432 B
  float4* WGP = (float4*)(ws + 33554432);           // 64*512*16  =    524,288 B
  float4* WCP = (float4*)(ws + 34078720);           // 64*256*16  =    262,144 B
  __half* XG  = (__half*)d_out;                     // 65536*512*2 = 64 MB (== out)
  float*  out = (float*)d_out;

  hipLaunchKernelGGL(pack_weights, dim3(192), dim3(256), 0, stream, Wg, Wc, WGP, WCP);
  hipLaunchKernelGGL(xproj_gemm, dim3(1024, 12), dim3(256), 0, stream, x, Wg, Wc, XG, XC);
  hipLaunchKernelGGL(gru_scan, dim3(32), dim3(512), 0, stream,
                     WGP, WCP, bg, bc, h0, XG, XC, out);
}

// Round 4
// 3678.373 us; speedup vs baseline: 3.5606x; 3.5606x over previous
//
#include <hip/hip_runtime.h>
#include <hip/hip_fp16.h>

#define SEQ   2048
#define IND   256
#define NN    256

typedef _Float16 h2_t __attribute__((ext_vector_type(2)));

__device__ __forceinline__ float dot2f(unsigned a, unsigned b, float c) {
#if __has_builtin(__builtin_amdgcn_fdot2)
  union { unsigned u; h2_t h; } ua, ub;
  ua.u = a; ub.u = b;
  return __builtin_amdgcn_fdot2(ua.h, ub.h, c, false);
#else
  union { unsigned u; __half2 h; } ua, ub;
  ua.u = a; ub.u = b;
  return fmaf(__low2float(ua.h), __low2float(ub.h),
              fmaf(__high2float(ua.h), __high2float(ub.h), c));
#endif
}

__device__ __forceinline__ float fast_sigmoid(float x) {
  float e = __expf(-x);
  return __builtin_amdgcn_rcpf(1.f + e);
}
__device__ __forceinline__ float fast_tanh(float x) {
  x = fminf(15.f, fmaxf(-15.f, x));
  float e = __expf(2.f * x);
  return (e - 1.f) * __builtin_amdgcn_rcpf(e + 1.f);
}

// ---------------- K0: pack recurrent weights to f16 half2, column-major --------
// WGH[col][k2] = half2(Wg[256+2k2][col], Wg[257+2k2][col])   col<512, k2<128
// WCH[n][k2]   = half2(Wc[256+2k2][n],  Wc[257+2k2][n])      n<256,  k2<128
__global__ void pack_weights(const float* __restrict__ Wg,
                             const float* __restrict__ Wc,
                             unsigned* __restrict__ WGH,
                             unsigned* __restrict__ WCH) {
  int idx = blockIdx.x * 256 + threadIdx.x;
  if (idx < 512 * 128) {
    int col = idx >> 7, k2 = idx & 127;
    __half2 p = __floats2half2_rn(Wg[(256 + 2 * k2) * 512 + col],
                                  Wg[(257 + 2 * k2) * 512 + col]);
    union { __half2 h; unsigned u; } cv; cv.h = p;
    WGH[idx] = cv.u;
  } else {
    int i2 = idx - 512 * 128;          // < 256*128
    int n = i2 >> 7, k2 = i2 & 127;
    __half2 p = __floats2half2_rn(Wc[(256 + 2 * k2) * 256 + n],
                                  Wc[(257 + 2 * k2) * 256 + n]);
    union { __half2 h; unsigned u; } cv; cv.h = p;
    WCH[i2] = cv.u;
  }
}

// ---------------- K1: x-projection GEMM (unchanged) ----------------------------
__global__ __launch_bounds__(256) void xproj_gemm(
    const float* __restrict__ x, const float* __restrict__ Wg,
    const float* __restrict__ Wc, __half* XG, __half* XC) {
  __shared__ float As[16][68];
  __shared__ float Bs[16][64];
  const int i0 = blockIdx.x * 64;
  const int j0 = blockIdx.y * 64;
  const int tid = threadIdx.x;
  const int tr = tid >> 4, tc = tid & 15;
  const int arow = tid >> 2, ac4 = (tid & 3) * 4;
  const int bk = tid >> 4, bj4 = (tid & 15) * 4;
  const bool isG = (j0 < 512);
  const float* B = isG ? Wg : Wc;
  const int ldb = isG ? 512 : 256;
  const int jb  = (isG ? j0 : (j0 - 512)) + bj4;
  float acc[4][4] = {};
  for (int k0 = 0; k0 < IND; k0 += 16) {
    float4 av = *(const float4*)&x[(size_t)(i0 + arow) * IND + k0 + ac4];
    As[ac4+0][arow] = av.x; As[ac4+1][arow] = av.y;
    As[ac4+2][arow] = av.z; As[ac4+3][arow] = av.w;
    *(float4*)&Bs[bk][bj4] = *(const float4*)&B[(size_t)(k0 + bk) * ldb + jb];
    __syncthreads();
#pragma unroll
    for (int k = 0; k < 16; ++k) {
      float4 a4 = *(const float4*)&As[k][tr * 4];
      float4 b4 = *(const float4*)&Bs[k][tc * 4];
      float a[4] = {a4.x, a4.y, a4.z, a4.w};
      float b[4] = {b4.x, b4.y, b4.z, b4.w};
#pragma unroll
      for (int r = 0; r < 4; ++r)
#pragma unroll
        for (int c = 0; c < 4; ++c) acc[r][c] = fmaf(a[r], b[c], acc[r][c]);
    }
    __syncthreads();
  }
  for (int r = 0; r < 4; ++r) {
    const size_t i = i0 + tr * 4 + r;
    const int j = j0 + tc * 4;
    __half2 p0 = __floats2half2_rn(acc[r][0], acc[r][1]);
    __half2 p1 = __floats2half2_rn(acc[r][2], acc[r][3]);
    union { __half2 h2[2]; uint2 u; } pk; pk.h2[0] = p0; pk.h2[1] = p1;
    if (isG) *(uint2*)&XG[i * 512 + j]         = pk.u;
    else     *(uint2*)&XC[i * 256 + (j - 512)] = pk.u;
  }
}

// ---------------- K2: register-resident GRU scan, one block per batch ----------
// 512 threads. Pair (2n, 2n+1): even = r-col n + cand k2[0,64); odd = u-col n+256
// + cand k2[64,128). Weights f16 in VGPRs (192/thread). h, r*h in LDS as f16
// (broadcast ds_read_b128). Pair-exchange via __shfl_xor. 2 barriers/step.
__global__ __launch_bounds__(512) void gru_scan(
    const unsigned* __restrict__ WGH, const unsigned* __restrict__ WCH,
    const float* __restrict__ bg, const float* __restrict__ bc,
    const float* __restrict__ h0,
    const __half* __restrict__ XG, const __half* __restrict__ XC,
    float* __restrict__ out) {
  __shared__ unsigned h2[128];
  __shared__ unsigned rh2[128];
  const int b  = blockIdx.x;
  const int j  = threadIdx.x;
  const int n  = j >> 1;
  const int kh = j & 1;
  const int gcol = kh ? (n + 256) : n;

  // --- load resident weights into registers (one-time) ---
  unsigned wg[128];
  {
    const uint4* p = (const uint4*)(WGH + (size_t)gcol * 128);
#pragma unroll
    for (int i = 0; i < 32; ++i) ((uint4*)wg)[i] = p[i];
  }
  unsigned wc[64];
  {
    const uint4* p = (const uint4*)(WCH + (size_t)n * 128 + (size_t)kh * 64);
#pragma unroll
    for (int i = 0; i < 16; ++i) ((uint4*)wc)[i] = p[i];
  }

  const float bgj = bg[gcol];
  const float bcn = bc[n];
  float hn = h0[b * NN + n];
  if (kh == 0) ((__half*)h2)[n] = __float2half_rn(hn);
  __syncthreads();

  const size_t rowbase = (size_t)b * SEQ;
  for (int t = 0; t < SEQ; ++t) {
    const size_t row = rowbase + t;
    // issue per-step global loads early (latency hidden under gate dots)
    const __half xgh = XG[row * 512 + gcol];
    __half xch = __float2half_rn(0.f);
    if (kh == 0) xch = XC[row * 256 + n];

    // ---- phase A: gate = sigmoid(xg + bg + h . Wcol) ----
    float a0 = 0.f, a1 = 0.f, a2 = 0.f, a3 = 0.f;
    const uint4* h4 = (const uint4*)h2;
#pragma unroll
    for (int c = 0; c < 32; ++c) {
      uint4 hv = h4[c];
      a0 = dot2f(wg[4 * c + 0], hv.x, a0);
      a1 = dot2f(wg[4 * c + 1], hv.y, a1);
      a2 = dot2f(wg[4 * c + 2], hv.z, a2);
      a3 = dot2f(wg[4 * c + 3], hv.w, a3);
    }
    float g = fast_sigmoid(bgj + __half2float(xgh) + ((a0 + a1) + (a2 + a3)));
    float ex = __shfl_xor(g, 1);
    float r = kh ? ex : g;
    float u = kh ? g : ex;
    if (kh == 0) ((__half*)rh2)[n] = __float2half_rn(r * hn);
    __syncthreads();   // rh2 ready; also orders XG reads before out write

    // ---- phase B: c = tanh(xc + bc + (r*h) . Wc_col), k split across pair ----
    float c0 = 0.f, c1 = 0.f, c2 = 0.f, c3 = 0.f;
    const uint4* r4 = (const uint4*)rh2 + kh * 16;
#pragma unroll
    for (int c = 0; c < 16; ++c) {
      uint4 rv = r4[c];
      c0 = dot2f(wc[4 * c + 0], rv.x, c0);
      c1 = dot2f(wc[4 * c + 1], rv.y, c1);
      c2 = dot2f(wc[4 * c + 2], rv.z, c2);
      c3 = dot2f(wc[4 * c + 3], rv.w, c3);
    }
    float cacc = (c0 + c1) + (c2 + c3);
    if (kh == 0) cacc += bcn + __half2float(xch);
    cacc += __shfl_xor(cacc, 1);
    const float cc = fast_tanh(cacc);
    hn = u * hn + (1.f - u) * cc;
    if (kh == 0) {
      out[row * 256 + n] = hn;          // overwrites XG row t (already consumed)
      ((__half*)h2)[n] = __float2half_rn(hn);
    }
    __syncthreads();   // h2 ready for next step
  }
}

extern "C" void kernel_launch(void* const* d_in, const int* in_sizes, int n_in,
                              void* d_out, int out_size, void* d_ws, size_t ws_size,
                              hipStream_t stream) {
  const float* x  = (const float*)d_in[0];
  const float* h0 = (const float*)d_in[1];
  const float* Wg = (const float*)d_in[2];
  const float* bg = (const float*)d_in[3];
  const float* Wc = (const float*)d_in[4];
  const float* bc = (const float*)d_in[5];

  char* ws = (char*)d_ws;
  __half*   XC  = (__half*)ws;                    // 65536*256*2 = 33,554,432 B
  unsigned* WGH = (unsigned*)(ws + 33554432);     // 512*128*4   =    262,144 B
  unsigned* WCH = (unsigned*)(ws + 33816576);     // 256*128*4   =    131,072 B
  __half*   XG  = (__half*)d_out;                 // 64 MB, reused as out
  float*    out = (float*)d_out;

  hipLaunchKernelGGL(pack_weights, dim3(384), dim3(256), 0, stream, Wg, Wc, WGH, WCH);
  hipLaunchKernelGGL(xproj_gemm, dim3(1024, 12), dim3(256), 0, stream, x, Wg, Wc, XG, XC);
  hipLaunchKernelGGL(gru_scan, dim3(32), dim3(512), 0, stream,
                     WGH, WCH, bg, bc, h0, XG, XC, out);
}

// Round 5
// 3475.202 us; speedup vs baseline: 3.7688x; 1.0585x over previous
//
#include <hip/hip_runtime.h>
#include <hip/hip_fp16.h>

#define SEQ   2048
#define IND   256
#define NN    256

typedef _Float16 h2_t __attribute__((ext_vector_type(2)));

__device__ __forceinline__ float dot2f(unsigned a, unsigned b, float c) {
#if __has_builtin(__builtin_amdgcn_fdot2)
  union { unsigned u; h2_t h; } ua, ub;
  ua.u = a; ub.u = b;
  return __builtin_amdgcn_fdot2(ua.h, ub.h, c, false);
#else
  union { unsigned u; __half2 h; } ua, ub;
  ua.u = a; ub.u = b;
  return fmaf(__low2float(ua.h), __low2float(ub.h),
              fmaf(__high2float(ua.h), __high2float(ub.h), c));
#endif
}

__device__ __forceinline__ float fast_sigmoid(float x) {
  float e = __expf(-x);
  return __builtin_amdgcn_rcpf(1.f + e);
}
__device__ __forceinline__ float fast_tanh(float x) {
  x = fminf(15.f, fmaxf(-15.f, x));
  float e = __expf(2.f * x);
  return (e - 1.f) * __builtin_amdgcn_rcpf(e + 1.f);
}

// ---------------- K0: pack weights for the k-split scan -------------------------
// Scan thread t (wave w=t>>6, lane l=t&63) owns:
//   gate cols j = l+64i (i<8), cand cols n = l+64i (i<4), k2-slice [16w,16w+16).
// slot = i*16+k (gate) or 128+i*16+k (cand); value = half2(Wrow[256+2k2][col],
// Wrow[257+2k2][col]), k2 = 16w+k.
// PK layout: u32 idx = (slot>>2)*2048 + t*4 + (slot&3)  (scan reads uint4
// PK4[(slot>>2)*512 + t] -> perfectly coalesced per instruction).
__global__ void pack_weights(const float* __restrict__ Wg,
                             const float* __restrict__ Wc,
                             unsigned* __restrict__ PK) {
  int idx = blockIdx.x * 256 + threadIdx.x;   // < 512*192 = 98304
  int s4  = idx >> 11;
  int rem = idx & 2047;
  int t   = rem >> 2;
  int slot = s4 * 4 + (rem & 3);
  int w = t >> 6, l = t & 63;
  float lo, hi;
  if (slot < 128) {
    int i = slot >> 4, k = slot & 15;
    int col = l + 64 * i;
    int k2 = 16 * w + k;
    lo = Wg[(256 + 2 * k2) * 512 + col];
    hi = Wg[(257 + 2 * k2) * 512 + col];
  } else {
    int s = slot - 128;
    int i = s >> 4, k = s & 15;
    int n = l + 64 * i;
    int k2 = 16 * w + k;
    lo = Wc[(256 + 2 * k2) * 256 + n];
    hi = Wc[(257 + 2 * k2) * 256 + n];
  }
  union { __half2 h; unsigned u; } cv;
  cv.h = __floats2half2_rn(lo, hi);
  PK[idx] = cv.u;
}

// ---------------- K1: x-projection GEMM (unchanged) ----------------------------
__global__ __launch_bounds__(256) void xproj_gemm(
    const float* __restrict__ x, const float* __restrict__ Wg,
    const float* __restrict__ Wc, __half* XG, __half* XC) {
  __shared__ float As[16][68];
  __shared__ float Bs[16][64];
  const int i0 = blockIdx.x * 64;
  const int j0 = blockIdx.y * 64;
  const int tid = threadIdx.x;
  const int tr = tid >> 4, tc = tid & 15;
  const int arow = tid >> 2, ac4 = (tid & 3) * 4;
  const int bk = tid >> 4, bj4 = (tid & 15) * 4;
  const bool isG = (j0 < 512);
  const float* B = isG ? Wg : Wc;
  const int ldb = isG ? 512 : 256;
  const int jb  = (isG ? j0 : (j0 - 512)) + bj4;
  float acc[4][4] = {};
  for (int k0 = 0; k0 < IND; k0 += 16) {
    float4 av = *(const float4*)&x[(size_t)(i0 + arow) * IND + k0 + ac4];
    As[ac4+0][arow] = av.x; As[ac4+1][arow] = av.y;
    As[ac4+2][arow] = av.z; As[ac4+3][arow] = av.w;
    *(float4*)&Bs[bk][bj4] = *(const float4*)&B[(size_t)(k0 + bk) * ldb + jb];
    __syncthreads();
#pragma unroll
    for (int k = 0; k < 16; ++k) {
      float4 a4 = *(const float4*)&As[k][tr * 4];
      float4 b4 = *(const float4*)&Bs[k][tc * 4];
      float a[4] = {a4.x, a4.y, a4.z, a4.w};
      float b[4] = {b4.x, b4.y, b4.z, b4.w};
#pragma unroll
      for (int r = 0; r < 4; ++r)
#pragma unroll
        for (int c = 0; c < 4; ++c) acc[r][c] = fmaf(a[r], b[c], acc[r][c]);
    }
    __syncthreads();
  }
  for (int r = 0; r < 4; ++r) {
    const size_t i = i0 + tr * 4 + r;
    const int j = j0 + tc * 4;
    __half2 p0 = __floats2half2_rn(acc[r][0], acc[r][1]);
    __half2 p1 = __floats2half2_rn(acc[r][2], acc[r][3]);
    union { __half2 h2[2]; uint2 u; } pk; pk.h2[0] = p0; pk.h2[1] = p1;
    if (isG) *(uint2*)&XG[i * 512 + j]         = pk.u;
    else     *(uint2*)&XC[i * 256 + (j - 512)] = pk.u;
  }
}

// ---------------- K2: k-split register-resident GRU scan -----------------------
// One block per batch, 512 threads = 8 waves. Wave w owns k-slice [32w,32w+32)
// (16 half2). Each lane: 8 gate cols + 4 cand cols, weights in 192 VGPRs
// (asm-anchored; __launch_bounds__(512,2) -> 256-VGPR budget).
// Per step: 4 broadcast b128 per wave per phase (64B h-slice), stride-9 f32
// partials in LDS (bank-bijective), 2-level reduce, 4 barriers.
__global__ __launch_bounds__(512, 2) void gru_scan(
    const unsigned* __restrict__ PK,
    const float* __restrict__ bg, const float* __restrict__ bc,
    const float* __restrict__ h0,
    const __half* __restrict__ XG, const __half* __restrict__ XC,
    float* __restrict__ out) {
  __shared__ unsigned h2s[128];      // h as 256 halves
  __shared__ unsigned rh2s[128];     // r*h as 256 halves
  __shared__ float pG[512 * 9];      // gate partials [col][wave], stride 9
  __shared__ float pC[256 * 9];      // cand partials
  __shared__ float uarr[256];
  const int b    = blockIdx.x;
  const int tid  = threadIdx.x;
  const int wave = tid >> 6, lane = tid & 63;

  // one-time: load 192 u32 of weights, coalesced, then anchor in VGPRs
  unsigned wreg[192];
  {
    const uint4* p = (const uint4*)PK + tid;
#pragma unroll
    for (int s4 = 0; s4 < 48; ++s4) ((uint4*)wreg)[s4] = p[s4 * 512];
  }
#pragma unroll
  for (int i = 0; i < 192; ++i) asm volatile("" : "+v"(wreg[i]));

  const float bgj = bg[tid];
  const float bcn = (tid < 256) ? bc[tid] : 0.f;
  float hn = 0.f;
  if (tid < 256) {
    hn = h0[b * NN + tid];
    ((__half*)h2s)[tid] = __float2half_rn(hn);
  }
  __syncthreads();

  const size_t rowbase = (size_t)b * SEQ;
  for (int t = 0; t < SEQ; ++t) {
    const size_t row = rowbase + t;
    // prefetch x-projections (used after BAR1/BAR3; loads precede out-writes)
    const float xg = __half2float(XG[row * 512 + tid]);
    float xc = 0.f;
    if (tid < 256) xc = __half2float(XC[row * 256 + tid]);

    // ---- phase A: gate partials over this wave's k-slice ----
    unsigned hk[16];
    {
      const uint4* hb = (const uint4*)h2s + wave * 4;   // wave-uniform: broadcast
      ((uint4*)hk)[0] = hb[0]; ((uint4*)hk)[1] = hb[1];
      ((uint4*)hk)[2] = hb[2]; ((uint4*)hk)[3] = hb[3];
    }
#pragma unroll
    for (int i = 0; i < 8; ++i) {
      float pa = 0.f;
#pragma unroll
      for (int k = 0; k < 16; ++k) pa = dot2f(wreg[i * 16 + k], hk[k], pa);
      pG[(lane + 64 * i) * 9 + wave] = pa;
    }
    __syncthreads();                                    // BAR1

    // ---- reduce A: thread j finalizes gate col j ----
    float s = bgj + xg;
#pragma unroll
    for (int w = 0; w < 8; ++w) s += pG[tid * 9 + w];
    const float g = fast_sigmoid(s);
    if (tid < 256) ((__half*)rh2s)[tid] = __float2half_rn(g * hn);
    else           uarr[tid - 256] = g;
    __syncthreads();                                    // BAR2

    // ---- phase B: cand partials over this wave's k-slice ----
    unsigned rk[16];
    {
      const uint4* rb = (const uint4*)rh2s + wave * 4;
      ((uint4*)rk)[0] = rb[0]; ((uint4*)rk)[1] = rb[1];
      ((uint4*)rk)[2] = rb[2]; ((uint4*)rk)[3] = rb[3];
    }
#pragma unroll
    for (int i = 0; i < 4; ++i) {
      float pc = 0.f;
#pragma unroll
      for (int k = 0; k < 16; ++k) pc = dot2f(wreg[128 + i * 16 + k], rk[k], pc);
      pC[(lane + 64 * i) * 9 + wave] = pc;
    }
    __syncthreads();                                    // BAR3

    // ---- reduce B: thread n finalizes state n ----
    if (tid < 256) {
      float sc = bcn + xc;
#pragma unroll
      for (int w = 0; w < 8; ++w) sc += pC[tid * 9 + w];
      const float c = fast_tanh(sc);
      const float u = uarr[tid];
      hn = u * hn + (1.f - u) * c;
      out[row * 256 + tid] = hn;      // overwrites XG row t (consumed pre-BAR1)
      ((__half*)h2s)[tid] = __float2half_rn(hn);
    }
    __syncthreads();                                    // BAR4
  }
}

extern "C" void kernel_launch(void* const* d_in, const int* in_sizes, int n_in,
                              void* d_out, int out_size, void* d_ws, size_t ws_size,
                              hipStream_t stream) {
  const float* x  = (const float*)d_in[0];
  const float* h0 = (const float*)d_in[1];
  const float* Wg = (const float*)d_in[2];
  const float* bg = (const float*)d_in[3];
  const float* Wc = (const float*)d_in[4];
  const float* bc = (const float*)d_in[5];

  char* ws = (char*)d_ws;
  __half*   XC = (__half*)ws;                     // 65536*256*2 = 33,554,432 B
  unsigned* PK = (unsigned*)(ws + 33554432);      // 512*192*4   =    393,216 B
  __half*   XG = (__half*)d_out;                  // 64 MB, reused as out
  float*    out = (float*)d_out;

  hipLaunchKernelGGL(pack_weights, dim3(384), dim3(256), 0, stream, Wg, Wc, PK);
  hipLaunchKernelGGL(xproj_gemm, dim3(1024, 12), dim3(256), 0, stream, x, Wg, Wc, XG, XC);
  hipLaunchKernelGGL(gru_scan, dim3(32), dim3(512), 0, stream,
                     PK, bg, bc, h0, XG, XC, out);
}